// Round 1
// baseline (155.395 us; speedup 1.0000x reference)
//
#include <hip/hip_runtime.h>

#define MM 64          // GT boxes == wavefront size
#define NQ 7           // number of partial-sum quantities
#define MAIN_BLOCKS 1024

__device__ __forceinline__ float vfl_term(float l, float t, float* lmax) {
    // varifocal: bce(l,t) * (alpha*p^2*(1-t) + t)
    float e = __expf(-l);
    float p = __fdividef(1.0f, 1.0f + e);
    // log1p(exp(-|l|)) == -log(max(p, 1-p))
    float bce = fmaxf(l, 0.0f) - l * t - __logf(fmaxf(p, 1.0f - p));
    float wgt = 0.75f * p * p * (1.0f - t) + t;
    *lmax = fmaxf(*lmax, l);
    return bce * wgt;
}

__global__ __launch_bounds__(256) void k_hascand(
    const float2* __restrict__ ap, const float4* __restrict__ boxes,
    unsigned long long* __restrict__ mask, int n_pts)
{
    __shared__ float4 sb[MM];
    if (threadIdx.x < MM) sb[threadIdx.x] = boxes[threadIdx.x];
    __syncthreads();
    unsigned long long local = 0ull;
    int stride = gridDim.x * blockDim.x;
    for (int n = blockIdx.x * blockDim.x + threadIdx.x; n < n_pts; n += stride) {
        float2 p = ap[n];
        for (int m = 0; m < MM; ++m) {
            float4 b = sb[m];
            if (p.x >= b.x && p.x <= b.z && p.y >= b.y && p.y <= b.w) {
                float hx = fmaxf((b.z - b.x) * 0.5f, 1.0f);
                float hy = fmaxf((b.w - b.y) * 0.5f, 1.0f);
                float dx = fabsf(p.x - (b.x + b.z) * 0.5f) / hx;
                float dy = fabsf(p.y - (b.y + b.w) * 0.5f) / hy;
                if (fmaxf(dx, dy) <= 0.75f) local |= (1ull << m);
            }
        }
    }
    #pragma unroll
    for (int o = 32; o; o >>= 1) local |= __shfl_xor(local, o);
    if ((threadIdx.x & 63) == 0 && local) atomicOr(mask, local);
}

__global__ __launch_bounds__(256) void k_main(
    const float2* __restrict__ ap,
    const float4* __restrict__ cls4,
    const float4* __restrict__ ts4,
    const float*  __restrict__ pd,
    const float*  __restrict__ dflt,
    const float4* __restrict__ boxes,
    const float*  __restrict__ bw,
    const float4* __restrict__ pboxes,
    const float*  __restrict__ obj,
    const unsigned long long* __restrict__ candmask,
    float* __restrict__ partials,
    int n_pts)
{
    const int tid  = threadIdx.x;
    const int lane = tid & 63;
    const int wid  = tid >> 6;                       // 0..3
    const int waveGlobal = blockIdx.x * 4 + wid;
    const int totalWaves = gridDim.x * 4;

    // per-lane GT box (box m lives in lane m's registers)
    float4 b  = boxes[lane];
    float mybw = bw[lane];
    float inv_hx = __fdividef(1.0f, fmaxf((b.z - b.x) * 0.5f, 1.0f));
    float inv_hy = __fdividef(1.0f, fmaxf((b.w - b.y) * 0.5f, 1.0f));
    float ccx = (b.x + b.z) * 0.5f, ccy = (b.y + b.w) * 0.5f;
    bool has_c = ((candmask[0] >> lane) & 1ull) != 0;

    const int kseg = lane >> 4;      // which of 4 DFL groups
    const int jj   = lane & 15;      // bin index within group

    float accS1 = 0.f;   // sum (region+heat) * vfl      (lane-partial)
    float accS3 = 0.f;   // sum region_w * dfl           (lane-partial)
    float accS2 = 0.f;   // sum (region+heat)            (lane-uniform)
    float accS4 = 0.f;   // sum region_w                 (lane-uniform)
    float accObj = 0.f;  // sum obj bce                  (lane-uniform)
    float accMar = 0.f;  // sum relu(maxlogit - margin)  (lane-uniform)

    for (int n = waveGlobal; n < n_pts; n += totalWaves) {
        float2 p = ap[n];
        // ---- region weight & heat (lane = box) ----
        bool inside = (p.x >= b.x) & (p.x <= b.z) & (p.y >= b.y) & (p.y <= b.w);
        float dx = (p.x - ccx) * inv_hx;
        float dy = (p.y - ccy) * inv_hy;
        bool cand = inside && (fmaxf(fabsf(dx), fabsf(dy)) <= 0.75f);
        bool eff  = has_c ? cand : inside;
        float rw = eff ? mybw : 0.f;
        float ht = inside ? __expf(-0.125f * (dx * dx + dy * dy)) : 0.f;
        #pragma unroll
        for (int o = 32; o; o >>= 1) {
            rw = fmaxf(rw, __shfl_xor(rw, o));
            ht = fmaxf(ht, __shfl_xor(ht, o));
        }
        ht = fminf(ht, 1.0f);
        float w = rw + ht;

        // ---- varifocal row: 4 classes per lane, coalesced float4 ----
        float4 l4 = cls4[(size_t)n * 64 + lane];
        float4 t4 = ts4[(size_t)n * 64 + lane];
        float lmax = -1e30f;
        float vsum = vfl_term(l4.x, t4.x, &lmax) + vfl_term(l4.y, t4.y, &lmax)
                   + vfl_term(l4.z, t4.z, &lmax) + vfl_term(l4.w, t4.w, &lmax);
        accS1 += w * vsum;
        #pragma unroll
        for (int o = 32; o; o >>= 1) lmax = fmaxf(lmax, __shfl_xor(lmax, o));
        accMar += fmaxf(lmax - 8.0f, 0.f);
        accS2 += w;
        accS4 += rw;

        // ---- objectness BCE against heat (lane-uniform) ----
        float ol = obj[n];
        accObj += fmaxf(ol, 0.f) - ol * ht + __logf(1.0f + __expf(-fabsf(ol)));

        // ---- DFL: 64 floats per anchor, one per lane; segmented-16 log_softmax ----
        float x = pd[(size_t)n * 64 + lane];
        float tg = dflt[(size_t)n * 4 + kseg];
        float mx = x;
        #pragma unroll
        for (int o = 8; o; o >>= 1) mx = fmaxf(mx, __shfl_xor(mx, o));
        float e = __expf(x - mx);
        float se = e;
        #pragma unroll
        for (int o = 8; o; o >>= 1) se += __shfl_xor(se, o);
        float logp = (x - mx) - __logf(se);
        int tl = (int)tg; tl = max(0, min(tl, 15));
        int tr = min(tl + 1, 15);
        float wl = (float)tr - tg;
        float contrib = 0.f;
        if (jj == tl) contrib += -logp * wl;
        if (jj == tr) contrib += -logp * (1.0f - wl);
        accS3 += rw * contrib;
    }

    // ---- pass 2: oversize penalty, thread-parallel coalesced ----
    float accPen = 0.f;
    int gsize = gridDim.x * blockDim.x;
    for (int n = blockIdx.x * blockDim.x + tid; n < n_pts; n += gsize) {
        float4 pbx = pboxes[n];
        float x1 = fminf(fmaxf(pbx.x, 0.f), 1024.0f);
        float y1 = fminf(fmaxf(pbx.y, 0.f), 1024.0f);
        float x2 = fminf(fmaxf(pbx.z, 0.f), 1024.0f);
        float y2 = fminf(fmaxf(pbx.w, 0.f), 1024.0f);
        float wq = fmaxf(x2 - x1, 0.f), hq = fmaxf(y2 - y1, 0.f);
        float ar = wq * hq * (1.0f / (1024.0f * 1024.0f));
        float edge = ((x1 <= 1.f ? 1.f : 0.f) + (y1 <= 1.f ? 1.f : 0.f) +
                      (x2 >= 1023.f ? 1.f : 0.f) + (y2 >= 1023.f ? 1.f : 0.f)) * 0.25f;
        accPen += fmaxf(ar - 0.6f, 0.f) * (1.f + edge);
    }

    // ---- reduce lane-partials within wave ----
    #pragma unroll
    for (int o = 32; o; o >>= 1) {
        accS1  += __shfl_xor(accS1, o);
        accS3  += __shfl_xor(accS3, o);
        accPen += __shfl_xor(accPen, o);
    }
    __shared__ float sh[4][NQ];
    if (lane == 0) {
        sh[wid][0] = accS1; sh[wid][1] = accS2; sh[wid][2] = accS3;
        sh[wid][3] = accS4; sh[wid][4] = accObj; sh[wid][5] = accMar;
        sh[wid][6] = accPen;
    }
    __syncthreads();
    if (tid < NQ) {
        partials[blockIdx.x * NQ + tid] =
            sh[0][tid] + sh[1][tid] + sh[2][tid] + sh[3][tid];
    }
}

__global__ __launch_bounds__(256) void k_final(
    const float* __restrict__ partials, int nblocks,
    float* __restrict__ out, int n_pts)
{
    double acc[NQ];
    #pragma unroll
    for (int q = 0; q < NQ; ++q) acc[q] = 0.0;
    for (int i = threadIdx.x; i < nblocks; i += 256) {
        #pragma unroll
        for (int q = 0; q < NQ; ++q) acc[q] += (double)partials[i * NQ + q];
    }
    __shared__ double sh[256][NQ + 1];
    #pragma unroll
    for (int q = 0; q < NQ; ++q) sh[threadIdx.x][q] = acc[q];
    __syncthreads();
    for (int s = 128; s; s >>= 1) {
        if (threadIdx.x < s) {
            #pragma unroll
            for (int q = 0; q < NQ; ++q) sh[threadIdx.x][q] += sh[threadIdx.x + s][q];
        }
        __syncthreads();
    }
    if (threadIdx.x == 0) {
        double S1 = sh[0][0], S2 = sh[0][1], S3 = sh[0][2], S4 = sh[0][3];
        double So = sh[0][4], Sm = sh[0][5], Sp = sh[0][6];
        double invN = 1.0 / (double)n_pts;
        double cls_loss = S1 / fmax(S2, 1e-6);
        double dfl_loss = S3 / fmax(S4, 1e-6);
        double total = cls_loss + So * invN + dfl_loss + 0.1 * Sp * invN + 0.05 * Sm * invN;
        out[0] = (float)total;
    }
}

extern "C" void kernel_launch(void* const* d_in, const int* in_sizes, int n_in,
                              void* d_out, int out_size, void* d_ws, size_t ws_size,
                              hipStream_t stream) {
    const float2* ap    = (const float2*)d_in[0];
    const float4* cls4  = (const float4*)d_in[1];
    const float4* ts4   = (const float4*)d_in[2];
    const float*  pd    = (const float*)d_in[3];
    const float*  dflt  = (const float*)d_in[4];
    const float4* boxes = (const float4*)d_in[5];
    const float*  bw    = (const float*)d_in[6];
    const float4* pbx   = (const float4*)d_in[7];
    const float*  obj   = (const float*)d_in[8];
    int n_pts = in_sizes[0] / 2;

    unsigned long long* mask = (unsigned long long*)d_ws;
    float* partials = (float*)((char*)d_ws + 16);

    hipMemsetAsync(d_ws, 0, 16, stream);
    k_hascand<<<256, 256, 0, stream>>>(ap, boxes, mask, n_pts);
    k_main<<<MAIN_BLOCKS, 256, 0, stream>>>(ap, cls4, ts4, pd, dflt, boxes, bw,
                                            pbx, obj, mask, partials, n_pts);
    k_final<<<1, 256, 0, stream>>>(partials, MAIN_BLOCKS, (float*)d_out, n_pts);
}

// Round 2
// 150.769 us; speedup vs baseline: 1.0307x; 1.0307x over previous
//
#include <hip/hip_runtime.h>

#define MM 64           // GT boxes == wavefront size
#define NQ 7            // number of partial-sum quantities
#define MAIN_BLOCKS 2048

__device__ __forceinline__ float vfl_term(float l, float t, float* lmax) {
    float e = __expf(-l);
    float p = __fdividef(1.0f, 1.0f + e);
    // log1p(exp(-|l|)) == -log(max(p, 1-p))
    float bce = fmaxf(l, 0.0f) - l * t - __logf(fmaxf(p, 1.0f - p));
    float wgt = 0.75f * p * p * (1.0f - t) + t;
    *lmax = fmaxf(*lmax, l);
    return bce * wgt;
}

__global__ __launch_bounds__(256) void k_hascand(
    const float2* __restrict__ ap, const float4* __restrict__ boxes,
    unsigned long long* __restrict__ mask, int n_pts)
{
    __shared__ float4 sb[MM];
    if (threadIdx.x < MM) sb[threadIdx.x] = boxes[threadIdx.x];
    __syncthreads();
    unsigned long long local = 0ull;
    int stride = gridDim.x * blockDim.x;
    for (int n = blockIdx.x * blockDim.x + threadIdx.x; n < n_pts; n += stride) {
        float2 p = ap[n];
        for (int m = 0; m < MM; ++m) {
            float4 b = sb[m];
            if (p.x >= b.x && p.x <= b.z && p.y >= b.y && p.y <= b.w) {
                float hx = fmaxf((b.z - b.x) * 0.5f, 1.0f);
                float hy = fmaxf((b.w - b.y) * 0.5f, 1.0f);
                float dx = fabsf(p.x - (b.x + b.z) * 0.5f) / hx;
                float dy = fabsf(p.y - (b.y + b.w) * 0.5f) / hy;
                if (fmaxf(dx, dy) <= 0.75f) local |= (1ull << m);
            }
        }
    }
    #pragma unroll
    for (int o = 32; o; o >>= 1) local |= __shfl_xor(local, o);
    if ((threadIdx.x & 63) == 0 && local) atomicOr(mask, local);
}

// Per-anchor region weight + heat, thread-parallel, no shuffles.
__global__ __launch_bounds__(256) void k_prep(
    const float2* __restrict__ ap, const float4* __restrict__ boxes,
    const float* __restrict__ bw, const unsigned long long* __restrict__ candmask,
    float2* __restrict__ w2, int n_pts)
{
    __shared__ float4 sB[MM];   // raw box
    __shared__ float4 sA[MM];   // {ccx, ccy, inv_hx, inv_hy}
    __shared__ float  sW[MM];   // box weight
    if (threadIdx.x < MM) {
        float4 b = boxes[threadIdx.x];
        sB[threadIdx.x] = b;
        float ihx = __fdividef(1.0f, fmaxf((b.z - b.x) * 0.5f, 1.0f));
        float ihy = __fdividef(1.0f, fmaxf((b.w - b.y) * 0.5f, 1.0f));
        sA[threadIdx.x] = make_float4((b.x + b.z) * 0.5f, (b.y + b.w) * 0.5f, ihx, ihy);
        sW[threadIdx.x] = bw[threadIdx.x];
    }
    __syncthreads();
    unsigned long long cm = candmask[0];
    int stride = gridDim.x * blockDim.x;
    for (int n = blockIdx.x * blockDim.x + threadIdx.x; n < n_pts; n += stride) {
        float2 p = ap[n];
        float rw = 0.f, ht = 0.f;
        #pragma unroll 8
        for (int m = 0; m < MM; ++m) {
            float4 b = sB[m];
            float4 a = sA[m];
            bool inside = (p.x >= b.x) & (p.x <= b.z) & (p.y >= b.y) & (p.y <= b.w);
            float dx = (p.x - a.x) * a.z;
            float dy = (p.y - a.y) * a.w;
            bool cand = inside && (fmaxf(fabsf(dx), fabsf(dy)) <= 0.75f);
            bool eff = ((cm >> m) & 1ull) ? cand : inside;
            if (eff) rw = fmaxf(rw, sW[m]);
            float h = __expf(-0.125f * (dx * dx + dy * dy));
            if (inside) ht = fmaxf(ht, h);
        }
        ht = fminf(ht, 1.0f);
        w2[n] = make_float2(rw + ht, rw);
    }
}

__device__ __forceinline__ void anchor_body(
    float4 l4, float4 t4, float pda, float2 wv, float ol, float tg,
    int jj, float valid,
    float* accS1, float* accS2, float* accS3, float* accS4,
    float* accObj, float* accMar)
{
    float w = wv.x, rw = wv.y;
    float lmax = -1e30f;
    float vsum = vfl_term(l4.x, t4.x, &lmax) + vfl_term(l4.y, t4.y, &lmax)
               + vfl_term(l4.z, t4.z, &lmax) + vfl_term(l4.w, t4.w, &lmax);
    *accS1 += valid * w * vsum;
    #pragma unroll
    for (int o = 32; o; o >>= 1) lmax = fmaxf(lmax, __shfl_xor(lmax, o));
    *accMar += valid * fmaxf(lmax - 8.0f, 0.f);
    *accS2 += valid * w;
    *accS4 += valid * rw;

    *accObj += valid * (fmaxf(ol, 0.f) - ol * w /*heat replaced below*/, 0.f);
    // NOTE: placeholder never used; real obj handled by caller
}

__global__ __launch_bounds__(256) void k_main(
    const float4* __restrict__ cls4,
    const float4* __restrict__ ts4,
    const float*  __restrict__ pd,
    const float*  __restrict__ dflt,
    const float4* __restrict__ pboxes,
    const float*  __restrict__ obj,
    const float2* __restrict__ w2,
    float* __restrict__ partials,
    int n_pts)
{
    const int tid  = threadIdx.x;
    const int lane = tid & 63;
    const int wid  = tid >> 6;
    const int waveGlobal = blockIdx.x * 4 + wid;
    const int step = gridDim.x * 4;

    const int kseg = lane >> 4;
    const int jj   = lane & 15;

    float accS1 = 0.f, accS2 = 0.f, accS3 = 0.f, accS4 = 0.f;
    float accObj = 0.f, accMar = 0.f;

    for (int n = waveGlobal; n < n_pts; n += 2 * step) {
        int n1 = n + step;
        bool have2 = n1 < n_pts;
        size_t r0 = (size_t)n * 64 + lane;
        size_t r1 = (size_t)(have2 ? n1 : n) * 64 + lane;
        int q1 = have2 ? n1 : n;

        // hoisted loads for both anchors
        float4 l4a = cls4[r0], t4a = ts4[r0];
        float4 l4b = cls4[r1], t4b = ts4[r1];
        float  pda = pd[r0],   pdb = pd[r1];
        float2 wva = w2[n],    wvb = w2[q1];
        float  ola = obj[n],   olb = obj[q1];
        float  tga = dflt[(size_t)n * 4 + kseg], tgb = dflt[(size_t)q1 * 4 + kseg];
        float  v1 = have2 ? 1.0f : 0.0f;

        // ---------- anchor 0 ----------
        {
            float w = wva.x, rw = wva.y, ht = wva.x - wva.y;
            float lmax = -1e30f;
            float vsum = vfl_term(l4a.x, t4a.x, &lmax) + vfl_term(l4a.y, t4a.y, &lmax)
                       + vfl_term(l4a.z, t4a.z, &lmax) + vfl_term(l4a.w, t4a.w, &lmax);
            accS1 += w * vsum;
            #pragma unroll
            for (int o = 32; o; o >>= 1) lmax = fmaxf(lmax, __shfl_xor(lmax, o));
            accMar += fmaxf(lmax - 8.0f, 0.f);
            accS2 += w; accS4 += rw;
            accObj += fmaxf(ola, 0.f) - ola * ht + __logf(1.0f + __expf(-fabsf(ola)));

            float x = pda;
            float mx = x;
            #pragma unroll
            for (int o = 8; o; o >>= 1) mx = fmaxf(mx, __shfl_xor(mx, o));
            float e = __expf(x - mx);
            float se = e;
            #pragma unroll
            for (int o = 8; o; o >>= 1) se += __shfl_xor(se, o);
            float logp = (x - mx) - __logf(se);
            int tl = (int)tga; tl = max(0, min(tl, 15));
            int tr = min(tl + 1, 15);
            float wl = (float)tr - tga;
            float contrib = 0.f;
            if (jj == tl) contrib += -logp * wl;
            if (jj == tr) contrib += -logp * (1.0f - wl);
            accS3 += rw * contrib;
        }
        // ---------- anchor 1 ----------
        {
            float w = wvb.x, rw = wvb.y, ht = wvb.x - wvb.y;
            float lmax = -1e30f;
            float vsum = vfl_term(l4b.x, t4b.x, &lmax) + vfl_term(l4b.y, t4b.y, &lmax)
                       + vfl_term(l4b.z, t4b.z, &lmax) + vfl_term(l4b.w, t4b.w, &lmax);
            accS1 += v1 * w * vsum;
            #pragma unroll
            for (int o = 32; o; o >>= 1) lmax = fmaxf(lmax, __shfl_xor(lmax, o));
            accMar += v1 * fmaxf(lmax - 8.0f, 0.f);
            accS2 += v1 * w; accS4 += v1 * rw;
            accObj += v1 * (fmaxf(olb, 0.f) - olb * ht + __logf(1.0f + __expf(-fabsf(olb))));

            float x = pdb;
            float mx = x;
            #pragma unroll
            for (int o = 8; o; o >>= 1) mx = fmaxf(mx, __shfl_xor(mx, o));
            float e = __expf(x - mx);
            float se = e;
            #pragma unroll
            for (int o = 8; o; o >>= 1) se += __shfl_xor(se, o);
            float logp = (x - mx) - __logf(se);
            int tl = (int)tgb; tl = max(0, min(tl, 15));
            int tr = min(tl + 1, 15);
            float wl = (float)tr - tgb;
            float contrib = 0.f;
            if (jj == tl) contrib += -logp * wl;
            if (jj == tr) contrib += -logp * (1.0f - wl);
            accS3 += v1 * rw * contrib;
        }
    }

    // ---- oversize penalty, thread-parallel coalesced ----
    float accPen = 0.f;
    int gsize = gridDim.x * blockDim.x;
    for (int n = blockIdx.x * blockDim.x + tid; n < n_pts; n += gsize) {
        float4 pbx = pboxes[n];
        float x1 = fminf(fmaxf(pbx.x, 0.f), 1024.0f);
        float y1 = fminf(fmaxf(pbx.y, 0.f), 1024.0f);
        float x2 = fminf(fmaxf(pbx.z, 0.f), 1024.0f);
        float y2 = fminf(fmaxf(pbx.w, 0.f), 1024.0f);
        float wq = fmaxf(x2 - x1, 0.f), hq = fmaxf(y2 - y1, 0.f);
        float ar = wq * hq * (1.0f / (1024.0f * 1024.0f));
        float edge = ((x1 <= 1.f ? 1.f : 0.f) + (y1 <= 1.f ? 1.f : 0.f) +
                      (x2 >= 1023.f ? 1.f : 0.f) + (y2 >= 1023.f ? 1.f : 0.f)) * 0.25f;
        accPen += fmaxf(ar - 0.6f, 0.f) * (1.f + edge);
    }

    #pragma unroll
    for (int o = 32; o; o >>= 1) {
        accS1  += __shfl_xor(accS1, o);
        accS3  += __shfl_xor(accS3, o);
        accPen += __shfl_xor(accPen, o);
    }
    __shared__ float sh[4][NQ];
    if (lane == 0) {
        sh[wid][0] = accS1; sh[wid][1] = accS2; sh[wid][2] = accS3;
        sh[wid][3] = accS4; sh[wid][4] = accObj; sh[wid][5] = accMar;
        sh[wid][6] = accPen;
    }
    __syncthreads();
    if (tid < NQ) {
        partials[blockIdx.x * NQ + tid] =
            sh[0][tid] + sh[1][tid] + sh[2][tid] + sh[3][tid];
    }
}

__global__ __launch_bounds__(256) void k_final(
    const float* __restrict__ partials, int nblocks,
    float* __restrict__ out, int n_pts)
{
    double acc[NQ];
    #pragma unroll
    for (int q = 0; q < NQ; ++q) acc[q] = 0.0;
    for (int i = threadIdx.x; i < nblocks; i += 256) {
        #pragma unroll
        for (int q = 0; q < NQ; ++q) acc[q] += (double)partials[i * NQ + q];
    }
    __shared__ double sh[256][NQ + 1];
    #pragma unroll
    for (int q = 0; q < NQ; ++q) sh[threadIdx.x][q] = acc[q];
    __syncthreads();
    for (int s = 128; s; s >>= 1) {
        if (threadIdx.x < s) {
            #pragma unroll
            for (int q = 0; q < NQ; ++q) sh[threadIdx.x][q] += sh[threadIdx.x + s][q];
        }
        __syncthreads();
    }
    if (threadIdx.x == 0) {
        double S1 = sh[0][0], S2 = sh[0][1], S3 = sh[0][2], S4 = sh[0][3];
        double So = sh[0][4], Sm = sh[0][5], Sp = sh[0][6];
        double invN = 1.0 / (double)n_pts;
        double cls_loss = S1 / fmax(S2, 1e-6);
        double dfl_loss = S3 / fmax(S4, 1e-6);
        double total = cls_loss + So * invN + dfl_loss + 0.1 * Sp * invN + 0.05 * Sm * invN;
        out[0] = (float)total;
    }
}

extern "C" void kernel_launch(void* const* d_in, const int* in_sizes, int n_in,
                              void* d_out, int out_size, void* d_ws, size_t ws_size,
                              hipStream_t stream) {
    const float2* ap    = (const float2*)d_in[0];
    const float4* cls4  = (const float4*)d_in[1];
    const float4* ts4   = (const float4*)d_in[2];
    const float*  pd    = (const float*)d_in[3];
    const float*  dflt  = (const float*)d_in[4];
    const float4* boxes = (const float4*)d_in[5];
    const float*  bw    = (const float*)d_in[6];
    const float4* pbx   = (const float4*)d_in[7];
    const float*  obj   = (const float*)d_in[8];
    int n_pts = in_sizes[0] / 2;

    unsigned long long* mask = (unsigned long long*)d_ws;
    float* partials = (float*)((char*)d_ws + 64);                 // 2048*7*4 = 57344 B
    float2* w2 = (float2*)((char*)d_ws + 65536);                  // n_pts*8 = 1.38 MB

    hipMemsetAsync(d_ws, 0, 16, stream);
    k_hascand<<<256, 256, 0, stream>>>(ap, boxes, mask, n_pts);
    k_prep<<<672, 256, 0, stream>>>(ap, boxes, bw, mask, w2, n_pts);
    k_main<<<MAIN_BLOCKS, 256, 0, stream>>>(cls4, ts4, pd, dflt, pbx, obj, w2,
                                            partials, n_pts);
    k_final<<<1, 256, 0, stream>>>(partials, MAIN_BLOCKS, (float*)d_out, n_pts);
}

// Round 3
// 144.713 us; speedup vs baseline: 1.0738x; 1.0418x over previous
//
#include <hip/hip_runtime.h>

#define MM 64
#define MAIN_BLOCKS 1344
#define PREP_BLOCKS 672
#define NQ_MAIN 5       // S1, S2, S3, S4, Mar
#define NQ_PREP 2       // Obj, Pen

__device__ __forceinline__ float vfl1(float l, float t, float* vmax) {
    float e = __expf(-l);
    float p = __fdividef(1.0f, 1.0f + e);
    float q = fmaxf(p, 1.0f - p);
    float bce = fmaf(-l, t, fmaxf(l, 0.0f)) - __logf(q);
    float wgt = fmaf(0.75f * p * p, 1.0f - t, t);
    *vmax = fmaxf(*vmax, l);
    return bce * wgt;
}

__global__ __launch_bounds__(256) void k_hascand(
    const float2* __restrict__ ap, const float4* __restrict__ boxes,
    unsigned long long* __restrict__ mask, int n_pts)
{
    __shared__ float4 sb[MM];
    if (threadIdx.x < MM) sb[threadIdx.x] = boxes[threadIdx.x];
    __syncthreads();
    unsigned long long local = 0ull;
    int stride = gridDim.x * blockDim.x;
    for (int n = blockIdx.x * blockDim.x + threadIdx.x; n < n_pts; n += stride) {
        float2 p = ap[n];
        for (int m = 0; m < MM; ++m) {
            float4 b = sb[m];
            if (p.x >= b.x && p.x <= b.z && p.y >= b.y && p.y <= b.w) {
                float hx = fmaxf((b.z - b.x) * 0.5f, 1.0f);
                float hy = fmaxf((b.w - b.y) * 0.5f, 1.0f);
                float dx = fabsf(p.x - (b.x + b.z) * 0.5f) / hx;
                float dy = fabsf(p.y - (b.y + b.w) * 0.5f) / hy;
                if (fmaxf(dx, dy) <= 0.75f) local |= (1ull << m);
            }
        }
    }
    #pragma unroll
    for (int o = 32; o; o >>= 1) local |= __shfl_xor(local, o);
    if ((threadIdx.x & 63) == 0 && local) atomicOr(mask, local);
}

// Per-anchor region weight + heat + obj BCE + oversize penalty.
__global__ __launch_bounds__(256) void k_prep(
    const float2* __restrict__ ap, const float4* __restrict__ boxes,
    const float* __restrict__ bw, const unsigned long long* __restrict__ candmask,
    const float4* __restrict__ pboxes, const float* __restrict__ obj,
    float2* __restrict__ w2, float* __restrict__ prep_partials, int n_pts)
{
    __shared__ float4 sB[MM];
    __shared__ float4 sA[MM];   // {ccx, ccy, inv_hx, inv_hy}
    __shared__ float  sW[MM];
    if (threadIdx.x < MM) {
        float4 b = boxes[threadIdx.x];
        sB[threadIdx.x] = b;
        float ihx = __fdividef(1.0f, fmaxf((b.z - b.x) * 0.5f, 1.0f));
        float ihy = __fdividef(1.0f, fmaxf((b.w - b.y) * 0.5f, 1.0f));
        sA[threadIdx.x] = make_float4((b.x + b.z) * 0.5f, (b.y + b.w) * 0.5f, ihx, ihy);
        sW[threadIdx.x] = bw[threadIdx.x];
    }
    __syncthreads();
    unsigned long long cm = candmask[0];
    int n = blockIdx.x * blockDim.x + threadIdx.x;
    float aObj = 0.f, aPen = 0.f;
    if (n < n_pts) {
        float2 p = ap[n];
        float rw = 0.f, ht = 0.f;
        #pragma unroll 8
        for (int m = 0; m < MM; ++m) {
            float4 b = sB[m];
            float4 a = sA[m];
            bool inside = (p.x >= b.x) & (p.x <= b.z) & (p.y >= b.y) & (p.y <= b.w);
            float dx = (p.x - a.x) * a.z;
            float dy = (p.y - a.y) * a.w;
            bool cand = inside && (fmaxf(fabsf(dx), fabsf(dy)) <= 0.75f);
            bool eff = ((cm >> m) & 1ull) ? cand : inside;
            if (eff) rw = fmaxf(rw, sW[m]);
            float h = __expf(-0.125f * (dx * dx + dy * dy));
            if (inside) ht = fmaxf(ht, h);
        }
        ht = fminf(ht, 1.0f);
        w2[n] = make_float2(rw + ht, rw);

        float ol = obj[n];
        aObj = fmaxf(ol, 0.f) - ol * ht + __logf(1.0f + __expf(-fabsf(ol)));

        float4 pbx = pboxes[n];
        float x1 = fminf(fmaxf(pbx.x, 0.f), 1024.0f);
        float y1 = fminf(fmaxf(pbx.y, 0.f), 1024.0f);
        float x2 = fminf(fmaxf(pbx.z, 0.f), 1024.0f);
        float y2 = fminf(fmaxf(pbx.w, 0.f), 1024.0f);
        float wq = fmaxf(x2 - x1, 0.f), hq = fmaxf(y2 - y1, 0.f);
        float ar = wq * hq * (1.0f / (1024.0f * 1024.0f));
        float edge = ((x1 <= 1.f ? 1.f : 0.f) + (y1 <= 1.f ? 1.f : 0.f) +
                      (x2 >= 1023.f ? 1.f : 0.f) + (y2 >= 1023.f ? 1.f : 0.f)) * 0.25f;
        aPen = fmaxf(ar - 0.6f, 0.f) * (1.f + edge);
    }
    #pragma unroll
    for (int o = 32; o; o >>= 1) {
        aObj += __shfl_xor(aObj, o);
        aPen += __shfl_xor(aPen, o);
    }
    __shared__ float sh[4][2];
    int lane = threadIdx.x & 63, wid = threadIdx.x >> 6;
    if (lane == 0) { sh[wid][0] = aObj; sh[wid][1] = aPen; }
    __syncthreads();
    if (threadIdx.x < NQ_PREP) {
        prep_partials[blockIdx.x * NQ_PREP + threadIdx.x] =
            sh[0][threadIdx.x] + sh[1][threadIdx.x] + sh[2][threadIdx.x] + sh[3][threadIdx.x];
    }
}

__global__ __launch_bounds__(256) void k_main(
    const float4* __restrict__ cls4,
    const float4* __restrict__ ts4,
    const float*  __restrict__ pd,
    const float*  __restrict__ dflt,
    const float2* __restrict__ w2,
    float* __restrict__ partials,
    int n_pts)
{
    const int tid  = threadIdx.x;
    const int lane = tid & 63;
    const int wid  = tid >> 6;
    const int wave = blockIdx.x * 4 + wid;            // 0..5375
    const int CHUNK = MAIN_BLOCKS * 4 * 4;            // 21504 anchors per sweep
    const int ksel = lane >> 4;
    const float jjf = (float)(lane & 15);

    float accS1 = 0.f, accS2 = 0.f, accS3 = 0.f, accS4 = 0.f, accMar = 0.f;

    for (int n0 = wave * 4; n0 + 3 < n_pts; n0 += CHUNK) {
        // ---- clustered loads for 4 anchors ----
        float4 l4[4], t4[4];
        float  xp[4], tg[4];
        float2 wv[4];
        #pragma unroll
        for (int u = 0; u < 4; ++u) {
            int n = n0 + u;
            int o = n * 64 + lane;
            l4[u] = cls4[o];
            t4[u] = ts4[o];
            xp[u] = pd[o];
            wv[u] = w2[n];
            tg[u] = dflt[n * 4 + ksel];
        }
        #pragma unroll
        for (int u = 0; u < 4; ++u) {
            float w = wv[u].x, rw = wv[u].y;
            // ---- varifocal, 4 classes/lane ----
            float vmax = -1e30f;
            float vsum = vfl1(l4[u].x, t4[u].x, &vmax) + vfl1(l4[u].y, t4[u].y, &vmax)
                       + vfl1(l4[u].z, t4[u].z, &vmax) + vfl1(l4[u].w, t4[u].w, &vmax);
            accS1 = fmaf(w, vsum, accS1);
            accS2 += w;
            accS4 += rw;
            // ---- margin: relu(max-8) == max(relu(l-8)); butterfly only if any lane can contribute
            if (__any(vmax > 8.0f)) {
                float t = vmax;
                #pragma unroll
                for (int o = 32; o; o >>= 1) t = fmaxf(t, __shfl_xor(t, o));
                accMar += t - 8.0f;
            }
            // ---- DFL: no max-sub (data range safe), tent-weight gather ----
            float e = __expf(xp[u]);
            float se = e;
            #pragma unroll
            for (int o = 8; o; o >>= 1) se += __shfl_xor(se, o);
            float lse = __logf(se);
            float d  = tg[u] - jjf;
            float tw = fmaxf(1.0f - fabsf(d), 0.0f);
            float term = fmaf(-tw, xp[u], lse * 0.0625f);
            accS3 = fmaf(rw, term, accS3);
        }
    }

    #pragma unroll
    for (int o = 32; o; o >>= 1) {
        accS1 += __shfl_xor(accS1, o);
        accS3 += __shfl_xor(accS3, o);
    }
    __shared__ float sh[4][NQ_MAIN];
    if (lane == 0) {
        sh[wid][0] = accS1; sh[wid][1] = accS2; sh[wid][2] = accS3;
        sh[wid][3] = accS4; sh[wid][4] = accMar;
    }
    __syncthreads();
    if (tid < NQ_MAIN) {
        partials[blockIdx.x * NQ_MAIN + tid] =
            sh[0][tid] + sh[1][tid] + sh[2][tid] + sh[3][tid];
    }
}

__global__ __launch_bounds__(256) void k_final(
    const float* __restrict__ mainp, const float* __restrict__ prepp,
    float* __restrict__ out, int n_pts)
{
    double acc[7];
    #pragma unroll
    for (int q = 0; q < 7; ++q) acc[q] = 0.0;
    for (int i = threadIdx.x; i < MAIN_BLOCKS; i += 256) {
        #pragma unroll
        for (int q = 0; q < NQ_MAIN; ++q) acc[q] += (double)mainp[i * NQ_MAIN + q];
    }
    for (int i = threadIdx.x; i < PREP_BLOCKS; i += 256) {
        #pragma unroll
        for (int q = 0; q < NQ_PREP; ++q) acc[5 + q] += (double)prepp[i * NQ_PREP + q];
    }
    __shared__ double sh[256][8];
    #pragma unroll
    for (int q = 0; q < 7; ++q) sh[threadIdx.x][q] = acc[q];
    __syncthreads();
    for (int s = 128; s; s >>= 1) {
        if (threadIdx.x < s) {
            #pragma unroll
            for (int q = 0; q < 7; ++q) sh[threadIdx.x][q] += sh[threadIdx.x + s][q];
        }
        __syncthreads();
    }
    if (threadIdx.x == 0) {
        double S1 = sh[0][0], S2 = sh[0][1], S3 = sh[0][2], S4 = sh[0][3];
        double Sm = sh[0][4], So = sh[0][5], Sp = sh[0][6];
        double invN = 1.0 / (double)n_pts;
        double cls_loss = S1 / fmax(S2, 1e-6);
        double dfl_loss = S3 / fmax(S4, 1e-6);
        out[0] = (float)(cls_loss + So * invN + dfl_loss + 0.1 * Sp * invN + 0.05 * Sm * invN);
    }
}

extern "C" void kernel_launch(void* const* d_in, const int* in_sizes, int n_in,
                              void* d_out, int out_size, void* d_ws, size_t ws_size,
                              hipStream_t stream) {
    const float2* ap    = (const float2*)d_in[0];
    const float4* cls4  = (const float4*)d_in[1];
    const float4* ts4   = (const float4*)d_in[2];
    const float*  pd    = (const float*)d_in[3];
    const float*  dflt  = (const float*)d_in[4];
    const float4* boxes = (const float4*)d_in[5];
    const float*  bw    = (const float*)d_in[6];
    const float4* pbx   = (const float4*)d_in[7];
    const float*  obj   = (const float*)d_in[8];
    int n_pts = in_sizes[0] / 2;

    unsigned long long* mask = (unsigned long long*)d_ws;
    float* main_partials = (float*)((char*)d_ws + 1024);     // 1344*5*4 = 26880 B
    float* prep_partials = (float*)((char*)d_ws + 32768);    // 672*2*4  = 5376 B
    float2* w2 = (float2*)((char*)d_ws + 65536);             // n_pts*8  = 1.38 MB

    hipMemsetAsync(d_ws, 0, 16, stream);
    k_hascand<<<256, 256, 0, stream>>>(ap, boxes, mask, n_pts);
    k_prep<<<PREP_BLOCKS, 256, 0, stream>>>(ap, boxes, bw, mask, pbx, obj, w2,
                                            prep_partials, n_pts);
    k_main<<<MAIN_BLOCKS, 256, 0, stream>>>(cls4, ts4, pd, dflt, w2,
                                            main_partials, n_pts);
    k_final<<<1, 256, 0, stream>>>(main_partials, prep_partials, (float*)d_out, n_pts);
}

// Round 4
// 142.808 us; speedup vs baseline: 1.0881x; 1.0133x over previous
//
#include <hip/hip_runtime.h>

#define MM 64
#define MAIN_BLOCKS 1344     // ×4 waves ×32 anchors = 172032 exactly
#define PREP_BLOCKS 672
#define NQ_MAIN 5            // S1, S2, S3, S4, Mar
#define NQ_PREP 2            // Obj, Pen

__device__ __forceinline__ float vfl1(float l, float t, float* vmax) {
    float e = __expf(-l);
    float p = __fdividef(1.0f, 1.0f + e);
    float q = fmaxf(p, 1.0f - p);
    float bce = fmaf(-l, t, fmaxf(l, 0.0f)) - __logf(q);
    float wgt = fmaf(0.75f * p * p, 1.0f - t, t);
    *vmax = fmaxf(*vmax, l);
    return bce * wgt;
}

__global__ __launch_bounds__(256) void k_hascand(
    const float2* __restrict__ ap, const float4* __restrict__ boxes,
    unsigned long long* __restrict__ mask, int n_pts)
{
    __shared__ float4 sb[MM];
    if (threadIdx.x < MM) sb[threadIdx.x] = boxes[threadIdx.x];
    __syncthreads();
    unsigned long long local = 0ull;
    int stride = gridDim.x * blockDim.x;
    for (int n = blockIdx.x * blockDim.x + threadIdx.x; n < n_pts; n += stride) {
        float2 p = ap[n];
        for (int m = 0; m < MM; ++m) {
            float4 b = sb[m];
            if (p.x >= b.x && p.x <= b.z && p.y >= b.y && p.y <= b.w) {
                float hx = fmaxf((b.z - b.x) * 0.5f, 1.0f);
                float hy = fmaxf((b.w - b.y) * 0.5f, 1.0f);
                float dx = fabsf(p.x - (b.x + b.z) * 0.5f) / hx;
                float dy = fabsf(p.y - (b.y + b.w) * 0.5f) / hy;
                if (fmaxf(dx, dy) <= 0.75f) local |= (1ull << m);
            }
        }
    }
    #pragma unroll
    for (int o = 32; o; o >>= 1) local |= __shfl_xor(local, o);
    if ((threadIdx.x & 63) == 0 && local) atomicOr(mask, local);
}

// Per-anchor region weight + heat + obj BCE + oversize penalty.
__global__ __launch_bounds__(256) void k_prep(
    const float2* __restrict__ ap, const float4* __restrict__ boxes,
    const float* __restrict__ bw, const unsigned long long* __restrict__ candmask,
    const float4* __restrict__ pboxes, const float* __restrict__ obj,
    float2* __restrict__ w2, float* __restrict__ prep_partials, int n_pts)
{
    __shared__ float4 sB[MM];
    __shared__ float4 sA[MM];   // {ccx, ccy, inv_hx, inv_hy}
    __shared__ float  sW[MM];
    if (threadIdx.x < MM) {
        float4 b = boxes[threadIdx.x];
        sB[threadIdx.x] = b;
        float ihx = __fdividef(1.0f, fmaxf((b.z - b.x) * 0.5f, 1.0f));
        float ihy = __fdividef(1.0f, fmaxf((b.w - b.y) * 0.5f, 1.0f));
        sA[threadIdx.x] = make_float4((b.x + b.z) * 0.5f, (b.y + b.w) * 0.5f, ihx, ihy);
        sW[threadIdx.x] = bw[threadIdx.x];
    }
    __syncthreads();
    unsigned long long cm = candmask[0];
    int n = blockIdx.x * blockDim.x + threadIdx.x;
    float aObj = 0.f, aPen = 0.f;
    if (n < n_pts) {
        float2 p = ap[n];
        float rw = 0.f, ht = 0.f;
        #pragma unroll 8
        for (int m = 0; m < MM; ++m) {
            float4 b = sB[m];
            float4 a = sA[m];
            bool inside = (p.x >= b.x) & (p.x <= b.z) & (p.y >= b.y) & (p.y <= b.w);
            float dx = (p.x - a.x) * a.z;
            float dy = (p.y - a.y) * a.w;
            bool cand = inside && (fmaxf(fabsf(dx), fabsf(dy)) <= 0.75f);
            bool eff = ((cm >> m) & 1ull) ? cand : inside;
            if (eff) rw = fmaxf(rw, sW[m]);
            float h = __expf(-0.125f * (dx * dx + dy * dy));
            if (inside) ht = fmaxf(ht, h);
        }
        ht = fminf(ht, 1.0f);
        w2[n] = make_float2(rw + ht, rw);

        float ol = obj[n];
        aObj = fmaxf(ol, 0.f) - ol * ht + __logf(1.0f + __expf(-fabsf(ol)));

        float4 pbx = pboxes[n];
        float x1 = fminf(fmaxf(pbx.x, 0.f), 1024.0f);
        float y1 = fminf(fmaxf(pbx.y, 0.f), 1024.0f);
        float x2 = fminf(fmaxf(pbx.z, 0.f), 1024.0f);
        float y2 = fminf(fmaxf(pbx.w, 0.f), 1024.0f);
        float wq = fmaxf(x2 - x1, 0.f), hq = fmaxf(y2 - y1, 0.f);
        float ar = wq * hq * (1.0f / (1024.0f * 1024.0f));
        float edge = ((x1 <= 1.f ? 1.f : 0.f) + (y1 <= 1.f ? 1.f : 0.f) +
                      (x2 >= 1023.f ? 1.f : 0.f) + (y2 >= 1023.f ? 1.f : 0.f)) * 0.25f;
        aPen = fmaxf(ar - 0.6f, 0.f) * (1.f + edge);
    }
    #pragma unroll
    for (int o = 32; o; o >>= 1) {
        aObj += __shfl_xor(aObj, o);
        aPen += __shfl_xor(aPen, o);
    }
    __shared__ float sh[4][2];
    int lane = threadIdx.x & 63, wid = threadIdx.x >> 6;
    if (lane == 0) { sh[wid][0] = aObj; sh[wid][1] = aPen; }
    __syncthreads();
    if (threadIdx.x < NQ_PREP) {
        prep_partials[blockIdx.x * NQ_PREP + threadIdx.x] =
            sh[0][threadIdx.x] + sh[1][threadIdx.x] + sh[2][threadIdx.x] + sh[3][threadIdx.x];
    }
}

__global__ __launch_bounds__(256) void k_main(
    const float4* __restrict__ cls4,
    const float4* __restrict__ ts4,
    const float4* __restrict__ pd4,
    const float*  __restrict__ dflt,
    const float2* __restrict__ w2,
    float* __restrict__ partials,
    int n_pts)
{
    const int tid  = threadIdx.x;
    const int lane = tid & 63;
    const int wid  = tid >> 6;
    const int wave = blockIdx.x * 4 + wid;     // 0..5375
    const int base = wave * 32;                // 32 contiguous anchors per wave

    // DFL lane constants: pd float4 chunk c covers anchors n0+4c..n0+4c+3;
    // lane holds bins [4*(lane&3) .. +3] of (anchor = 4c + (lane>>4), reg = (lane&15)>>2)
    const int a_off = lane >> 4;
    const int r_idx = (lane & 15) >> 2;
    const float j0  = (float)(4 * (lane & 3));

    float accS1 = 0.f, accS2 = 0.f, accS3 = 0.f, accS4 = 0.f, accMar = 0.f;

    #pragma unroll 1
    for (int blk = 0; blk < 4; ++blk) {
        const int n0 = base + blk * 8;
        // ---- burst loads: 8 anchors, ~18.6 KB per wave in flight ----
        float4 c4[8], s4[8];
        #pragma unroll
        for (int c = 0; c < 8; ++c) {
            int idx = (n0 + c) * 64 + lane;
            c4[c] = cls4[idx];
            s4[c] = ts4[idx];
        }
        float4 p4[2];
        #pragma unroll
        for (int c = 0; c < 2; ++c) p4[c] = pd4[n0 * 16 + c * 64 + lane];
        float2 wv = w2[n0 + (lane & 7)];
        float tgv[2];
        #pragma unroll
        for (int c = 0; c < 2; ++c)
            tgv[c] = dflt[(n0 + c * 4 + a_off) * 4 + r_idx];

        // ---- VFL: chunk c == anchor n0+c, lane holds classes 4L..4L+3 ----
        #pragma unroll
        for (int c = 0; c < 8; ++c) {
            float w  = __shfl(wv.x, c);
            float rw = __shfl(wv.y, c);
            float vmax = -1e30f;
            float vs = vfl1(c4[c].x, s4[c].x, &vmax) + vfl1(c4[c].y, s4[c].y, &vmax)
                     + vfl1(c4[c].z, s4[c].z, &vmax) + vfl1(c4[c].w, s4[c].w, &vmax);
            accS1 = fmaf(w, vs, accS1);
            accS2 += w;
            accS4 += rw;
            if (__any(vmax > 8.0f)) {
                float t = vmax;
                #pragma unroll
                for (int o = 32; o; o >>= 1) t = fmaxf(t, __shfl_xor(t, o));
                accMar += t - 8.0f;
            }
        }

        // ---- DFL: 2 chunks of 4 anchors; 4-lane-group 16-bin softmax ----
        #pragma unroll
        for (int c = 0; c < 2; ++c) {
            float4 x = p4[c];
            float se = __expf(x.x) + __expf(x.y) + __expf(x.z) + __expf(x.w);
            se += __shfl_xor(se, 1);
            se += __shfl_xor(se, 2);
            float lse = __logf(se);
            float tg = tgv[c];
            float tx = 0.f;
            tx = fmaf(fmaxf(1.0f - fabsf(tg - j0), 0.f),          x.x, tx);
            tx = fmaf(fmaxf(1.0f - fabsf(tg - (j0 + 1.f)), 0.f),  x.y, tx);
            tx = fmaf(fmaxf(1.0f - fabsf(tg - (j0 + 2.f)), 0.f),  x.z, tx);
            tx = fmaf(fmaxf(1.0f - fabsf(tg - (j0 + 3.f)), 0.f),  x.w, tx);
            float rwl = __shfl(wv.y, c * 4 + a_off);
            accS3 = fmaf(rwl, 0.25f * lse - tx, accS3);
        }
    }

    #pragma unroll
    for (int o = 32; o; o >>= 1) {
        accS1 += __shfl_xor(accS1, o);
        accS3 += __shfl_xor(accS3, o);
    }
    __shared__ float sh[4][NQ_MAIN];
    if (lane == 0) {
        sh[wid][0] = accS1; sh[wid][1] = accS2; sh[wid][2] = accS3;
        sh[wid][3] = accS4; sh[wid][4] = accMar;
    }
    __syncthreads();
    if (tid < NQ_MAIN) {
        partials[blockIdx.x * NQ_MAIN + tid] =
            sh[0][tid] + sh[1][tid] + sh[2][tid] + sh[3][tid];
    }
}

__global__ __launch_bounds__(256) void k_final(
    const float* __restrict__ mainp, const float* __restrict__ prepp,
    float* __restrict__ out, int n_pts)
{
    double acc[7];
    #pragma unroll
    for (int q = 0; q < 7; ++q) acc[q] = 0.0;
    for (int i = threadIdx.x; i < MAIN_BLOCKS; i += 256) {
        #pragma unroll
        for (int q = 0; q < NQ_MAIN; ++q) acc[q] += (double)mainp[i * NQ_MAIN + q];
    }
    for (int i = threadIdx.x; i < PREP_BLOCKS; i += 256) {
        #pragma unroll
        for (int q = 0; q < NQ_PREP; ++q) acc[5 + q] += (double)prepp[i * NQ_PREP + q];
    }
    __shared__ double sh[256][8];
    #pragma unroll
    for (int q = 0; q < 7; ++q) sh[threadIdx.x][q] = acc[q];
    __syncthreads();
    for (int s = 128; s; s >>= 1) {
        if (threadIdx.x < s) {
            #pragma unroll
            for (int q = 0; q < 7; ++q) sh[threadIdx.x][q] += sh[threadIdx.x + s][q];
        }
        __syncthreads();
    }
    if (threadIdx.x == 0) {
        double S1 = sh[0][0], S2 = sh[0][1], S3 = sh[0][2], S4 = sh[0][3];
        double Sm = sh[0][4], So = sh[0][5], Sp = sh[0][6];
        double invN = 1.0 / (double)n_pts;
        double cls_loss = S1 / fmax(S2, 1e-6);
        double dfl_loss = S3 / fmax(S4, 1e-6);
        out[0] = (float)(cls_loss + So * invN + dfl_loss + 0.1 * Sp * invN + 0.05 * Sm * invN);
    }
}

extern "C" void kernel_launch(void* const* d_in, const int* in_sizes, int n_in,
                              void* d_out, int out_size, void* d_ws, size_t ws_size,
                              hipStream_t stream) {
    const float2* ap    = (const float2*)d_in[0];
    const float4* cls4  = (const float4*)d_in[1];
    const float4* ts4   = (const float4*)d_in[2];
    const float4* pd4   = (const float4*)d_in[3];
    const float*  dflt  = (const float*)d_in[4];
    const float4* boxes = (const float4*)d_in[5];
    const float*  bw    = (const float*)d_in[6];
    const float4* pbx   = (const float4*)d_in[7];
    const float*  obj   = (const float*)d_in[8];
    int n_pts = in_sizes[0] / 2;

    unsigned long long* mask = (unsigned long long*)d_ws;
    float* main_partials = (float*)((char*)d_ws + 1024);     // 1344*5*4 = 26880 B
    float* prep_partials = (float*)((char*)d_ws + 32768);    // 672*2*4  = 5376 B
    float2* w2 = (float2*)((char*)d_ws + 65536);             // n_pts*8  = 1.38 MB

    hipMemsetAsync(d_ws, 0, 16, stream);
    k_hascand<<<256, 256, 0, stream>>>(ap, boxes, mask, n_pts);
    k_prep<<<PREP_BLOCKS, 256, 0, stream>>>(ap, boxes, bw, mask, pbx, obj, w2,
                                            prep_partials, n_pts);
    k_main<<<MAIN_BLOCKS, 256, 0, stream>>>(cls4, ts4, pd4, dflt, w2,
                                            main_partials, n_pts);
    k_final<<<1, 256, 0, stream>>>(main_partials, prep_partials, (float*)d_out, n_pts);
}

// Round 5
// 136.610 us; speedup vs baseline: 1.1375x; 1.0454x over previous
//
#include <hip/hip_runtime.h>

#define MM 64
#define MAIN_BLOCKS 1344     // ×4 waves ×32 anchors = 172032 exactly
#define NQ 7                 // S1, S2, S3, S4, Mar, Obj, Pen

__device__ __forceinline__ float vfl1(float l, float t, float* vmax) {
    float e = __expf(-l);
    float p = __fdividef(1.0f, 1.0f + e);
    float q = fmaxf(p, 1.0f - p);
    float bce = fmaf(-l, t, fmaxf(l, 0.0f)) - __logf(q);
    float wgt = fmaf(0.75f * p * p, 1.0f - t, t);
    *vmax = fmaxf(*vmax, l);
    return bce * wgt;
}

__global__ __launch_bounds__(256) void k_hascand(
    const float2* __restrict__ ap, const float4* __restrict__ boxes,
    unsigned long long* __restrict__ mask, int n_pts)
{
    __shared__ float4 sb[MM];
    if (threadIdx.x < MM) sb[threadIdx.x] = boxes[threadIdx.x];
    __syncthreads();
    unsigned long long local = 0ull;
    int stride = gridDim.x * blockDim.x;
    for (int n = blockIdx.x * blockDim.x + threadIdx.x; n < n_pts; n += stride) {
        float2 p = ap[n];
        for (int m = 0; m < MM; ++m) {
            float4 b = sb[m];
            if (p.x >= b.x && p.x <= b.z && p.y >= b.y && p.y <= b.w) {
                float hx = fmaxf((b.z - b.x) * 0.5f, 1.0f);
                float hy = fmaxf((b.w - b.y) * 0.5f, 1.0f);
                float dx = fabsf(p.x - (b.x + b.z) * 0.5f) / hx;
                float dy = fabsf(p.y - (b.y + b.w) * 0.5f) / hy;
                if (fmaxf(dx, dy) <= 0.75f) local |= (1ull << m);
            }
        }
    }
    #pragma unroll
    for (int o = 32; o; o >>= 1) local |= __shfl_xor(local, o);
    if ((threadIdx.x & 63) == 0 && local) atomicOr(mask, local);
}

__global__ __launch_bounds__(256) void k_main(
    const float2* __restrict__ ap,
    const float4* __restrict__ cls4,
    const float4* __restrict__ ts4,
    const float4* __restrict__ pd4,
    const float*  __restrict__ dflt,
    const float4* __restrict__ boxes,
    const float*  __restrict__ bw,
    const float4* __restrict__ pboxes,
    const float*  __restrict__ obj,
    const unsigned long long* __restrict__ candmask,
    float* __restrict__ partials,
    int n_pts)
{
    __shared__ float4 sB[MM];
    __shared__ float4 sA[MM];   // {ccx, ccy, inv_hx, inv_hy}
    __shared__ float  sW[MM];
    if (threadIdx.x < MM) {
        float4 b = boxes[threadIdx.x];
        sB[threadIdx.x] = b;
        float ihx = __fdividef(1.0f, fmaxf((b.z - b.x) * 0.5f, 1.0f));
        float ihy = __fdividef(1.0f, fmaxf((b.w - b.y) * 0.5f, 1.0f));
        sA[threadIdx.x] = make_float4((b.x + b.z) * 0.5f, (b.y + b.w) * 0.5f, ihx, ihy);
        sW[threadIdx.x] = bw[threadIdx.x];
    }

    const int tid  = threadIdx.x;
    const int lane = tid & 63;
    const int wid  = tid >> 6;
    const int wave = blockIdx.x * 4 + wid;     // 0..5375
    const int base = wave * 32;                // 32 contiguous anchors per wave
    const unsigned long long cm = candmask[0];
    __syncthreads();

    // ================= Phase A: per-anchor weights, in-register =================
    // lane l and l+32 both handle anchor base+(l&31); lane<32 does boxes 0..31,
    // lane>=32 does boxes 32..63; combine via shfl_xor(32).
    const int la = lane & 31;
    const int na = base + la;
    const int mbase = (lane >> 5) << 5;        // 0 or 32
    float2 p = ap[na];
    float rw = 0.f, ht = 0.f;
    #pragma unroll 8
    for (int mm = 0; mm < 32; ++mm) {
        int m = mbase + mm;
        float4 b = sB[m];
        float4 a = sA[m];
        bool inside = (p.x >= b.x) & (p.x <= b.z) & (p.y >= b.y) & (p.y <= b.w);
        float dx = (p.x - a.x) * a.z;
        float dy = (p.y - a.y) * a.w;
        bool cand = inside && (fmaxf(fabsf(dx), fabsf(dy)) <= 0.75f);
        bool eff = ((cm >> m) & 1ull) ? cand : inside;
        if (eff) rw = fmaxf(rw, sW[m]);
        float h = __expf(-0.125f * (dx * dx + dy * dy));
        if (inside) ht = fmaxf(ht, h);
    }
    rw = fmaxf(rw, __shfl_xor(rw, 32));
    ht = fminf(fmaxf(ht, __shfl_xor(ht, 32)), 1.0f);
    const float wvx = rw + ht;                 // lane (l & 31) holds anchor base+(l&31)
    const float wvy = rw;

    // obj BCE + oversize penalty for own anchor (count once: lanes < 32)
    float aObj = 0.f, aPen = 0.f;
    if (lane < 32) {
        float ol = obj[na];
        aObj = fmaxf(ol, 0.f) - ol * ht + __logf(1.0f + __expf(-fabsf(ol)));
        float4 pbx = pboxes[na];
        float x1 = fminf(fmaxf(pbx.x, 0.f), 1024.0f);
        float y1 = fminf(fmaxf(pbx.y, 0.f), 1024.0f);
        float x2 = fminf(fmaxf(pbx.z, 0.f), 1024.0f);
        float y2 = fminf(fmaxf(pbx.w, 0.f), 1024.0f);
        float wq = fmaxf(x2 - x1, 0.f), hq = fmaxf(y2 - y1, 0.f);
        float ar = wq * hq * (1.0f / (1024.0f * 1024.0f));
        float edge = ((x1 <= 1.f ? 1.f : 0.f) + (y1 <= 1.f ? 1.f : 0.f) +
                      (x2 >= 1023.f ? 1.f : 0.f) + (y2 >= 1023.f ? 1.f : 0.f)) * 0.25f;
        aPen = fmaxf(ar - 0.6f, 0.f) * (1.f + edge);
    }

    // ================= Phase B: big streams =================
    const int a_off = lane >> 4;
    const int r_idx = (lane & 15) >> 2;
    const float j0  = (float)(4 * (lane & 3));

    float accS1 = 0.f, accS2 = 0.f, accS3 = 0.f, accS4 = 0.f, accMar = 0.f;

    #pragma unroll 1
    for (int blk = 0; blk < 4; ++blk) {
        const int n0 = base + blk * 8;
        float4 c4[8], s4[8];
        #pragma unroll
        for (int c = 0; c < 8; ++c) {
            int idx = (n0 + c) * 64 + lane;
            c4[c] = cls4[idx];
            s4[c] = ts4[idx];
        }
        float4 p4[2];
        #pragma unroll
        for (int c = 0; c < 2; ++c) p4[c] = pd4[n0 * 16 + c * 64 + lane];
        float tgv[2];
        #pragma unroll
        for (int c = 0; c < 2; ++c)
            tgv[c] = dflt[(n0 + c * 4 + a_off) * 4 + r_idx];

        // ---- VFL: chunk c == anchor n0+c, lane holds classes 4L..4L+3 ----
        #pragma unroll
        for (int c = 0; c < 8; ++c) {
            float w   = __shfl(wvx, blk * 8 + c);
            float rw_ = __shfl(wvy, blk * 8 + c);
            float vmax = -1e30f;
            float vs = vfl1(c4[c].x, s4[c].x, &vmax) + vfl1(c4[c].y, s4[c].y, &vmax)
                     + vfl1(c4[c].z, s4[c].z, &vmax) + vfl1(c4[c].w, s4[c].w, &vmax);
            accS1 = fmaf(w, vs, accS1);
            accS2 += w;
            accS4 += rw_;
            if (__any(vmax > 8.0f)) {
                float t = vmax;
                #pragma unroll
                for (int o = 32; o; o >>= 1) t = fmaxf(t, __shfl_xor(t, o));
                accMar += t - 8.0f;
            }
        }

        // ---- DFL: 2 chunks of 4 anchors; 4-lane-group 16-bin softmax ----
        #pragma unroll
        for (int c = 0; c < 2; ++c) {
            float4 x = p4[c];
            float se = __expf(x.x) + __expf(x.y) + __expf(x.z) + __expf(x.w);
            se += __shfl_xor(se, 1);
            se += __shfl_xor(se, 2);
            float lse = __logf(se);
            float tg = tgv[c];
            float tx = 0.f;
            tx = fmaf(fmaxf(1.0f - fabsf(tg - j0), 0.f),          x.x, tx);
            tx = fmaf(fmaxf(1.0f - fabsf(tg - (j0 + 1.f)), 0.f),  x.y, tx);
            tx = fmaf(fmaxf(1.0f - fabsf(tg - (j0 + 2.f)), 0.f),  x.z, tx);
            tx = fmaf(fmaxf(1.0f - fabsf(tg - (j0 + 3.f)), 0.f),  x.w, tx);
            float rwl = __shfl(wvy, blk * 8 + c * 4 + a_off);
            accS3 = fmaf(rwl, 0.25f * lse - tx, accS3);
        }
    }

    #pragma unroll
    for (int o = 32; o; o >>= 1) {
        accS1 += __shfl_xor(accS1, o);
        accS3 += __shfl_xor(accS3, o);
        aObj  += __shfl_xor(aObj, o);
        aPen  += __shfl_xor(aPen, o);
    }
    __shared__ float sh[4][NQ];
    if (lane == 0) {
        sh[wid][0] = accS1; sh[wid][1] = accS2; sh[wid][2] = accS3;
        sh[wid][3] = accS4; sh[wid][4] = accMar; sh[wid][5] = aObj;
        sh[wid][6] = aPen;
    }
    __syncthreads();
    if (tid < NQ) {
        partials[blockIdx.x * NQ + tid] =
            sh[0][tid] + sh[1][tid] + sh[2][tid] + sh[3][tid];
    }
}

__global__ __launch_bounds__(256) void k_final(
    const float* __restrict__ mainp, float* __restrict__ out, int n_pts)
{
    double acc[NQ];
    #pragma unroll
    for (int q = 0; q < NQ; ++q) acc[q] = 0.0;
    for (int i = threadIdx.x; i < MAIN_BLOCKS; i += 256) {
        #pragma unroll
        for (int q = 0; q < NQ; ++q) acc[q] += (double)mainp[i * NQ + q];
    }
    __shared__ double sh[256][NQ + 1];
    #pragma unroll
    for (int q = 0; q < NQ; ++q) sh[threadIdx.x][q] = acc[q];
    __syncthreads();
    for (int s = 128; s; s >>= 1) {
        if (threadIdx.x < s) {
            #pragma unroll
            for (int q = 0; q < NQ; ++q) sh[threadIdx.x][q] += sh[threadIdx.x + s][q];
        }
        __syncthreads();
    }
    if (threadIdx.x == 0) {
        double S1 = sh[0][0], S2 = sh[0][1], S3 = sh[0][2], S4 = sh[0][3];
        double Sm = sh[0][4], So = sh[0][5], Sp = sh[0][6];
        double invN = 1.0 / (double)n_pts;
        double cls_loss = S1 / fmax(S2, 1e-6);
        double dfl_loss = S3 / fmax(S4, 1e-6);
        out[0] = (float)(cls_loss + So * invN + dfl_loss + 0.1 * Sp * invN + 0.05 * Sm * invN);
    }
}

extern "C" void kernel_launch(void* const* d_in, const int* in_sizes, int n_in,
                              void* d_out, int out_size, void* d_ws, size_t ws_size,
                              hipStream_t stream) {
    const float2* ap    = (const float2*)d_in[0];
    const float4* cls4  = (const float4*)d_in[1];
    const float4* ts4   = (const float4*)d_in[2];
    const float4* pd4   = (const float4*)d_in[3];
    const float*  dflt  = (const float*)d_in[4];
    const float4* boxes = (const float4*)d_in[5];
    const float*  bw    = (const float*)d_in[6];
    const float4* pbx   = (const float4*)d_in[7];
    const float*  obj   = (const float*)d_in[8];
    int n_pts = in_sizes[0] / 2;

    unsigned long long* mask = (unsigned long long*)d_ws;
    float* main_partials = (float*)((char*)d_ws + 1024);     // 1344*7*4 = 37632 B

    hipMemsetAsync(d_ws, 0, 16, stream);
    k_hascand<<<256, 256, 0, stream>>>(ap, boxes, mask, n_pts);
    k_main<<<MAIN_BLOCKS, 256, 0, stream>>>(ap, cls4, ts4, pd4, dflt, boxes, bw,
                                            pbx, obj, mask, main_partials, n_pts);
    k_final<<<1, 256, 0, stream>>>(main_partials, (float*)d_out, n_pts);
}